// Round 5
// baseline (1344.436 us; speedup 1.0000x reference)
//
#include <hip/hip_runtime.h>
#include <hip/hip_bf16.h>
#include <math.h>

typedef unsigned short u16;
typedef __attribute__((ext_vector_type(4))) unsigned short u16x4;
typedef __attribute__((ext_vector_type(8))) __bf16 bf16x8;
typedef __attribute__((ext_vector_type(4))) float fx4;

#define DEV __device__ __forceinline__

DEV u16 f2bf(float f) {  // RNE float->bf16
    unsigned u = __float_as_uint(f);
    u += 0x7fffu + ((u >> 16) & 1u);
    return (u16)(u >> 16);
}

DEV void async_load16(const void* g, void* l) {
    __builtin_amdgcn_global_load_lds(
        (const __attribute__((address_space(1))) void*)g,
        (__attribute__((address_space(3))) void*)l, 16, 0, 0);
}

DEV void block_reduce2(float& a, float& b) {
    #pragma unroll
    for (int o = 32; o; o >>= 1) { a += __shfl_xor(a, o); b += __shfl_xor(b, o); }
    __shared__ float sa[4], sb[4];
    const int lane = threadIdx.x & 63, wv = threadIdx.x >> 6;
    if (lane == 0) { sa[wv] = a; sb[wv] = b; }
    __syncthreads();
    a = sa[0] + sa[1] + sa[2] + sa[3];
    b = sb[0] + sb[1] + sb[2] + sb[3];
    __syncthreads();
}

// T1 XCD swizzle (chunked, bijective when total%8==0)
DEV void xcd_swizzle3(int& bx, int& by, int& bz) {
    const int nx = gridDim.x, ny = gridDim.y;
    const int total = nx * ny * gridDim.z;
    const int lin = blockIdx.x + nx * (blockIdx.y + ny * blockIdx.z);
    if (total & 7) { bx = blockIdx.x; by = blockIdx.y; bz = blockIdx.z; return; }
    const int cpx = total >> 3;
    const int swz = (lin & 7) * cpx + (lin >> 3);
    bx = swz % nx;
    const int r = swz / nx;
    by = r % ny;
    bz = r / ny;
}

// ---------------- LayerNorm, WAVE-per-row: no barriers, row lives in 16 VGPRs.
// 4 waves/block, each owns one row. Padded rows (>= rows_real) -> zeros.
__global__ __launch_bounds__(256) void ln_wave_k(
    const float* __restrict__ in, int rows_real, int rows_pad,
    const float* __restrict__ w, const float* __restrict__ bias,
    u16* __restrict__ out_bf, float* __restrict__ out_f32, float out_scale)
{
    const int wv = threadIdx.x >> 6, lane = threadIdx.x & 63;
    const int r = blockIdx.x * 4 + wv, b = blockIdx.y;
    const size_t orow = ((size_t)b * rows_pad + r) * 1024 + lane * 4;
    if (r >= rows_real) {
        u16x4 z = {0, 0, 0, 0};
        fx4 zf = {0.f, 0.f, 0.f, 0.f};
        #pragma unroll
        for (int c = 0; c < 4; ++c) {
            *(u16x4*)&out_bf[orow + c * 256] = z;
            if (out_f32) *(fx4*)&out_f32[orow + c * 256] = zf;
        }
        return;
    }
    const size_t irow = ((size_t)b * rows_real + r) * 1024 + lane * 4;
    fx4 x[4];
    float s1 = 0.f, s2 = 0.f;
    #pragma unroll
    for (int c = 0; c < 4; ++c) {
        x[c] = *(const fx4*)&in[irow + c * 256];
        s1 += x[c].x + x[c].y + x[c].z + x[c].w;
        s2 += x[c].x * x[c].x + x[c].y * x[c].y + x[c].z * x[c].z + x[c].w * x[c].w;
    }
    #pragma unroll
    for (int o = 32; o; o >>= 1) { s1 += __shfl_xor(s1, o); s2 += __shfl_xor(s2, o); }
    const float m = s1 * (1.0f / 1024.0f);
    const float var = s2 * (1.0f / 1024.0f) - m * m;
    const float rs = rsqrtf(var + 1e-5f);
    #pragma unroll
    for (int c = 0; c < 4; ++c) {
        fx4 wv4 = *(const fx4*)&w[c * 256 + lane * 4];
        fx4 bv4 = *(const fx4*)&bias[c * 256 + lane * 4];
        fx4 y;
        y.x = (x[c].x - m) * rs * wv4.x + bv4.x;
        y.y = (x[c].y - m) * rs * wv4.y + bv4.y;
        y.z = (x[c].z - m) * rs * wv4.z + bv4.z;
        y.w = (x[c].w - m) * rs * wv4.w + bv4.w;
        // out_scale is a power of two (2^-5) -> exact under RNE bf16 rounding
        u16x4 o = { f2bf(y.x * out_scale), f2bf(y.y * out_scale),
                    f2bf(y.z * out_scale), f2bf(y.w * out_scale) };
        *(u16x4*)&out_bf[orow + c * 256] = o;
        if (out_f32) *(fx4*)&out_f32[orow + c * 256] = y;
    }
}

// ---------------- 128x128 bf16 GEMM core (2-phase dbuf) — small self-attn gemms only
template<bool ATOMIC>
DEV void gemm_body(
    const u16* __restrict__ Ab, const u16* __restrict__ Bb, float* __restrict__ Cb,
    int k_begin, int iters, int lda, int ldb, int ldc)
{
    __shared__ u16 lA[2][128 * 32];
    __shared__ u16 lB[2][128 * 32];
    const int lane = threadIdx.x & 63, wv = threadIdx.x >> 6;
    const int wm = (wv >> 1) * 64, wn = (wv & 1) * 64;
    const int frow = lane & 15, quad = lane >> 4;

    fx4 acc[4][4];
    #pragma unroll
    for (int i = 0; i < 4; ++i)
        #pragma unroll
        for (int j = 0; j < 4; ++j) { acc[i][j].x = 0; acc[i][j].y = 0; acc[i][j].z = 0; acc[i][j].w = 0; }

    const int c0 = wv * 64 + lane;
    const int r0a = c0 >> 2, s0 = (c0 & 3) * 8;
    const int c1 = 256 + c0;
    const int r1a = c1 >> 2, s1 = (c1 & 3) * 8;

    auto stage = [&](int buf, int it) {
        const int k0 = k_begin + it * 32;
        async_load16(Ab + (size_t)r0a * lda + k0 + s0, &lA[buf][(wv * 64) * 8]);
        async_load16(Ab + (size_t)r1a * lda + k0 + s1, &lA[buf][(256 + wv * 64) * 8]);
        async_load16(Bb + (size_t)r0a * ldb + k0 + s0, &lB[buf][(wv * 64) * 8]);
        async_load16(Bb + (size_t)r1a * ldb + k0 + s1, &lB[buf][(256 + wv * 64) * 8]);
    };

    stage(0, 0);
    __syncthreads();
    int cur = 0;
    for (int it = 0; it < iters; ++it) {
        if (it + 1 < iters) stage(cur ^ 1, it + 1);
        bf16x8 af[4], bfr[4];
        #pragma unroll
        for (int i = 0; i < 4; ++i) {
            af[i]  = *(const bf16x8*)&lA[cur][(wm + i * 16 + frow) * 32 + quad * 8];
            bfr[i] = *(const bf16x8*)&lB[cur][(wn + i * 16 + frow) * 32 + quad * 8];
        }
        #pragma unroll
        for (int mi = 0; mi < 4; ++mi)
            #pragma unroll
            for (int ni = 0; ni < 4; ++ni)
                acc[mi][ni] = __builtin_amdgcn_mfma_f32_16x16x32_bf16(af[mi], bfr[ni], acc[mi][ni], 0, 0, 0);
        __syncthreads();
        cur ^= 1;
    }

    #pragma unroll
    for (int mi = 0; mi < 4; ++mi) {
        #pragma unroll
        for (int r = 0; r < 4; ++r) {
            const int row = wm + mi * 16 + quad * 4 + r;
            #pragma unroll
            for (int ni = 0; ni < 4; ++ni) {
                const int col = wn + ni * 16 + frow;
                if (ATOMIC) atomicAdd(&Cb[(size_t)row * ldc + col], acc[mi][ni][r]);
                else        Cb[(size_t)row * ldc + col] = acc[mi][ni][r];
            }
        }
    }
}

template<int NS>
__global__ __launch_bounds__(256) void gemm_bt_sk(
    const u16* __restrict__ A, const u16* __restrict__ B, float* __restrict__ C,
    int iters_per, int lda, int ldb, int ldc, long As, long Bs, long Cs)
{
    int bx, by, bzz;
    xcd_swizzle3(bx, by, bzz);
    const int bz = bzz / NS, sp = bzz % NS;
    const u16* Ab = A + (size_t)bz * As + (size_t)by * 128 * lda;
    const u16* Bb = B + (size_t)bz * Bs + (size_t)bx * 128 * ldb;
    float* Cb = C + (size_t)bz * Cs + (size_t)by * 128 * ldc + (size_t)bx * 128;
    gemm_body<true>(Ab, Bb, Cb, sp * iters_per * 32, iters_per, lda, ldb, ldc);
}

// ================= 256x256 8-phase GEMM (T2 swizzle + T4 counted vmcnt + T5 setprio) ======
// Identical structure to round 4 (verified correct); only change: non-atomic C-store is now
// a PLAIN store (S1 is re-read by softmax within the L3 window — NT hint defeated LLC reuse).
template<bool ATOMIC>
DEV void gemm256_body(
    const u16* __restrict__ A, const u16* __restrict__ B, float* __restrict__ C,
    int k_begin, int NT, int lda, int ldb, int ldc, int bx, int by, int Mreal)
{
    __shared__ u16 lds[2][4][8192];   // [buf][A0,A1,B0,B1][128*64]
    const int tid = threadIdx.x;
    const int lane = tid & 63, wid = tid >> 6;
    const int wr = wid >> 2, wc = wid & 3;
    const int frow = lane & 15, quad = lane >> 4;
    const int sw = (frow & 7) << 4;                 // T2 read-side XOR (bytes)
    const int csrc = ((lane & 7) ^ ((lane >> 3) & 7)) * 8;  // pre-swizzled source chunk (elems)
    const int by256 = by * 256, bx256 = bx * 256;
    const int mclamp = Mreal - 1;

    fx4 acc[8][4];
    #pragma unroll
    for (int i = 0; i < 8; ++i)
        #pragma unroll
        for (int j = 0; j < 4; ++j) { acc[i][j].x = 0; acc[i][j].y = 0; acc[i][j].z = 0; acc[i][j].w = 0; }

    auto stageA = [&](int buf, int half, int ktile) {
        const int kcol = k_begin + ktile * 64;
        #pragma unroll
        for (int j = 0; j < 2; ++j) {
            int grow = by256 + half * 128 + (wid * 2 + j) * 8 + (lane >> 3);
            if (grow > mclamp) grow = mclamp;
            async_load16(A + (size_t)grow * lda + kcol + csrc,
                         &lds[buf][half][(wid * 2 + j) * 512]);
        }
    };
    auto stageB = [&](int buf, int half, int ktile) {
        const int kcol = k_begin + ktile * 64;
        #pragma unroll
        for (int j = 0; j < 2; ++j) {
            const int grow = bx256 + half * 128 + (wid * 2 + j) * 8 + (lane >> 3);
            async_load16(B + (size_t)grow * ldb + kcol + csrc,
                         &lds[buf][2 + half][(wid * 2 + j) * 512]);
        }
    };

#define DO_PHASE(MQ, NQ, STAGE_STMT, WAITN)                                              \
    {                                                                                    \
        STAGE_STMT;                                                                      \
        __builtin_amdgcn_sched_barrier(0);                                               \
        asm volatile("s_waitcnt vmcnt(" #WAITN ")" ::: "memory");                        \
        __builtin_amdgcn_s_barrier();                                                    \
        __builtin_amdgcn_sched_barrier(0);                                               \
        const char* pa = (const char*)&lds[cur][MQ][0];                                  \
        const char* pb = (const char*)&lds[cur][2 + NQ][0];                              \
        bf16x8 av[4][2], bv[2][2];                                                       \
        _Pragma("unroll")                                                                \
        for (int f = 0; f < 4; ++f) {                                                    \
            const int row = wr * 64 + f * 16 + frow;                                     \
            _Pragma("unroll")                                                            \
            for (int ks = 0; ks < 2; ++ks)                                               \
                av[f][ks] = *(const bf16x8*)(pa + row * 128 + ((((ks * 4 + quad) << 4)) ^ sw)); \
        }                                                                                \
        _Pragma("unroll")                                                                \
        for (int gg = 0; gg < 2; ++gg) {                                                 \
            const int col = wc * 32 + gg * 16 + frow;                                    \
            _Pragma("unroll")                                                            \
            for (int ks = 0; ks < 2; ++ks)                                               \
                bv[gg][ks] = *(const bf16x8*)(pb + col * 128 + ((((ks * 4 + quad) << 4)) ^ sw)); \
        }                                                                                \
        __builtin_amdgcn_s_setprio(1);                                                   \
        _Pragma("unroll")                                                                \
        for (int f = 0; f < 4; ++f)                                                      \
            _Pragma("unroll")                                                            \
            for (int gg = 0; gg < 2; ++gg)                                               \
                _Pragma("unroll")                                                        \
                for (int ks = 0; ks < 2; ++ks)                                           \
                    acc[MQ * 4 + f][NQ * 2 + gg] = __builtin_amdgcn_mfma_f32_16x16x32_bf16( \
                        av[f][ks], bv[gg][ks], acc[MQ * 4 + f][NQ * 2 + gg], 0, 0, 0);   \
        __builtin_amdgcn_s_setprio(0);                                                   \
    }

    // prologue stage order: A0(0), B0(0), B1(0), A1(0), A0(1)
    stageA(0, 0, 0);
    stageB(0, 0, 0);
    stageB(0, 1, 0);
    stageA(0, 1, 0);
    stageA(1, 0, 1);

    int cur = 0;
    for (int t = 0; t <= NT - 2; ++t) {
        const int nxt = cur ^ 1;
        DO_PHASE(0, 0, stageB(nxt, 0, t + 1), 8)
        DO_PHASE(0, 1, stageB(nxt, 1, t + 1), 8)
        DO_PHASE(1, 0, stageA(nxt, 1, t + 1), 8)
        DO_PHASE(1, 1, if (t + 2 < NT) stageA(cur, 0, t + 2), 8)
        cur = nxt;
    }
    // peeled last tile: no stages, draining counted waits
    DO_PHASE(0, 0, (void)0, 4)
    DO_PHASE(0, 1, (void)0, 2)
    DO_PHASE(1, 0, (void)0, 0)
    DO_PHASE(1, 1, (void)0, 0)
#undef DO_PHASE

    #pragma unroll
    for (int mf = 0; mf < 8; ++mf) {
        const int rowb = (mf >> 2) * 128 + wr * 64 + (mf & 3) * 16 + quad * 4;
        #pragma unroll
        for (int r = 0; r < 4; ++r) {
            const int grow = by256 + rowb + r;
            if (grow < Mreal) {
                #pragma unroll
                for (int nf = 0; nf < 4; ++nf) {
                    const int gcol = bx256 + (nf >> 1) * 128 + wc * 32 + (nf & 1) * 16 + frow;
                    if (ATOMIC) atomicAdd(&C[(size_t)grow * ldc + gcol], acc[mf][nf][r]);
                    else C[(size_t)grow * ldc + gcol] = acc[mf][nf][r];  // plain: keep S1 in LLC
                }
            }
        }
    }
}

// QK^T: bx-major remap (A panel stays cache-resident; B slice shared by consecutive blocks)
__global__ __launch_bounds__(512, 2) void gemm256_qk(
    const u16* __restrict__ A, const u16* __restrict__ B, float* __restrict__ C,
    int NT, int lda, int ldb, int ldc, long As, long Bs, long Cs, int Mreal)
{
    const int lin = blockIdx.x + gridDim.x * (blockIdx.y + gridDim.y * blockIdx.z);
    const int per_bx = gridDim.y * gridDim.z;
    const int bx = lin / per_bx, rem = lin % per_bx;
    const int by = rem % gridDim.y, bz = rem / gridDim.y;
    gemm256_body<false>(A + (size_t)bz * As, B + (size_t)bz * Bs, C + (size_t)bz * Cs,
                        0, NT, lda, ldb, ldc, bx, by, Mreal);
}

// PV: split-K, XCD-chunked swizzle, atomic into pre-zeroed C
template<int NS>
__global__ __launch_bounds__(512, 2) void gemm256_sk(
    const u16* __restrict__ A, const u16* __restrict__ B, float* __restrict__ C,
    int NT_per, int lda, int ldb, int ldc, long As, long Bs, long Cs, int Mreal)
{
    int bx, by, bzz;
    xcd_swizzle3(bx, by, bzz);
    const int bz = bzz / NS, sp = bzz % NS;
    gemm256_body<true>(A + (size_t)bz * As, B + (size_t)bz * Bs, C + (size_t)bz * Cs,
                       sp * NT_per * 64, NT_per, lda, ldb, ldc, bx, by, Mreal);
}

// ---------------- row softmax (fx4-vectorized)
template<int EPT4>
__global__ __launch_bounds__(256) void softmax_k(
    const float* __restrict__ S, u16* __restrict__ P,
    int n_real, int n_pad, float scale, long Ss, long Ps)
{
    const int tid = threadIdx.x;
    const float* Sr = S + (size_t)blockIdx.y * Ss + (size_t)blockIdx.x * n_pad;
    u16* Pr = P + (size_t)blockIdx.y * Ps + (size_t)blockIdx.x * n_pad;
    fx4 v[EPT4];
    float mx = -INFINITY;
    #pragma unroll
    for (int i = 0; i < EPT4; ++i) {
        const int base = (i * 256 + tid) * 4;
        fx4 s;
        if (base < n_pad) s = *(const fx4*)&Sr[base];
        else { s.x = -INFINITY; s.y = -INFINITY; s.z = -INFINITY; s.w = -INFINITY; }
        s.x = (base + 0 < n_real) ? s.x * scale : -INFINITY;
        s.y = (base + 1 < n_real) ? s.y * scale : -INFINITY;
        s.z = (base + 2 < n_real) ? s.z * scale : -INFINITY;
        s.w = (base + 3 < n_real) ? s.w * scale : -INFINITY;
        v[i] = s;
        mx = fmaxf(mx, fmaxf(fmaxf(s.x, s.y), fmaxf(s.z, s.w)));
    }
    #pragma unroll
    for (int o = 32; o; o >>= 1) mx = fmaxf(mx, __shfl_xor(mx, o));
    __shared__ float sm[4];
    const int lane = tid & 63, wvi = tid >> 6;
    if (lane == 0) sm[wvi] = mx;
    __syncthreads();
    mx = fmaxf(fmaxf(sm[0], sm[1]), fmaxf(sm[2], sm[3]));
    __syncthreads();
    float sum = 0.f;
    #pragma unroll
    for (int i = 0; i < EPT4; ++i) {
        fx4 e;
        e.x = __expf(v[i].x - mx); e.y = __expf(v[i].y - mx);
        e.z = __expf(v[i].z - mx); e.w = __expf(v[i].w - mx);
        v[i] = e;
        sum += e.x + e.y + e.z + e.w;
    }
    #pragma unroll
    for (int o = 32; o; o >>= 1) sum += __shfl_xor(sum, o);
    if (lane == 0) sm[wvi] = sum;
    __syncthreads();
    sum = sm[0] + sm[1] + sm[2] + sm[3];
    const float inv = 1.0f / sum;
    #pragma unroll
    for (int i = 0; i < EPT4; ++i) {
        const int base = (i * 256 + tid) * 4;
        if (base < n_pad) {
            u16x4 o = { f2bf(v[i].x * inv), f2bf(v[i].y * inv),
                        f2bf(v[i].z * inv), f2bf(v[i].w * inv) };
            *(u16x4*)&Pr[base] = o;
        }
    }
}

// ---------------- bf16 transpose, 64x64 tile, 8B/lane global both sides.
__global__ __launch_bounds__(256) void transpose_k(
    const u16* __restrict__ in, u16* __restrict__ out,
    int in_rows, int in_cols, long is, long os)
{
    __shared__ u16 t[64][68];
    const int b = blockIdx.z;
    const u16* I = in + (size_t)b * is;
    u16* O = out + (size_t)b * os;
    const int c0 = blockIdx.x * 64, r0 = blockIdx.y * 64;
    const int cx = threadIdx.x & 15, ry = threadIdx.x >> 4;
    u16x4 a[4];
    #pragma unroll
    for (int k = 0; k < 4; ++k)
        a[k] = *(const u16x4*)&I[(size_t)(r0 + 4 * ry + k) * in_cols + c0 + 4 * cx];
    #pragma unroll
    for (int e = 0; e < 4; ++e) {
        u16x4 o = { a[0][e], a[1][e], a[2][e], a[3][e] };
        *(u16x4*)&t[4 * cx + e][4 * ry] = o;
    }
    __syncthreads();
    #pragma unroll
    for (int k = 0; k < 4; ++k) {
        const int oc = 4 * ry + k;
        *(u16x4*)&O[(size_t)(c0 + oc) * in_rows + r0 + 4 * cx] =
            *(const u16x4*)&t[oc][4 * cx];
    }
}

// ---------------- fused MLP (H=4, exact-erf GELU) + LayerNorm3; block per row
__global__ __launch_bounds__(256) void mlp_ln_k(
    const float* __restrict__ att, const float* __restrict__ w1, const float* __restrict__ b1,
    const float* __restrict__ w2, const float* __restrict__ b2,
    const float* __restrict__ w3, const float* __restrict__ b3,
    float* __restrict__ ca, u16* __restrict__ nc, int rows_real)
{
    const int q = blockIdx.x, b = blockIdx.y, tid = threadIdx.x;
    const size_t row = ((size_t)b * gridDim.x + q) * 1024 + tid * 4;
    if (q >= rows_real) {
        fx4 zf = {0.f, 0.f, 0.f, 0.f}; u16x4 z = {0, 0, 0, 0};
        *(fx4*)&ca[row] = zf;
        *(u16x4*)&nc[row] = z;
        return;
    }
    fx4 x = *(const fx4*)&att[row];
    float p[4];
    #pragma unroll
    for (int j = 0; j < 4; ++j) {
        fx4 wj = *(const fx4*)&w1[j * 1024 + tid * 4];
        p[j] = x.x * wj.x + x.y * wj.y + x.z * wj.z + x.w * wj.w;
        #pragma unroll
        for (int o = 32; o; o >>= 1) p[j] += __shfl_xor(p[j], o);
    }
    __shared__ float sh[4][4];
    const int lane = tid & 63, wvi = tid >> 6;
    if (lane == 0) { sh[wvi][0] = p[0]; sh[wvi][1] = p[1]; sh[wvi][2] = p[2]; sh[wvi][3] = p[3]; }
    __syncthreads();
    float h[4];
    #pragma unroll
    for (int j = 0; j < 4; ++j) {
        float s = sh[0][j] + sh[1][j] + sh[2][j] + sh[3][j] + b1[j];
        h[j] = 0.5f * s * (1.0f + erff(s * 0.70710678118f));
    }
    float v[4]; float s1 = 0.f, s2 = 0.f;
    #pragma unroll
    for (int e = 0; e < 4; ++e) {
        const int d = tid * 4 + e;
        fx4 wd = *(const fx4*)&w2[d * 4];
        float t = h[0] * wd.x + h[1] * wd.y + h[2] * wd.z + h[3] * wd.w + b2[d];
        v[e] = t; s1 += t; s2 += t * t;
    }
    block_reduce2(s1, s2);
    const float m = s1 * (1.0f / 1024.0f);
    const float var = s2 * (1.0f / 1024.0f) - m * m;
    const float rs = rsqrtf(var + 1e-5f);
    fx4 cav = {v[0], v[1], v[2], v[3]};
    *(fx4*)&ca[row] = cav;
    fx4 w3v = *(const fx4*)&w3[tid * 4], b3v = *(const fx4*)&b3[tid * 4];
    u16x4 o = { f2bf((v[0] - m) * rs * w3v.x + b3v.x), f2bf((v[1] - m) * rs * w3v.y + b3v.y),
                f2bf((v[2] - m) * rs * w3v.z + b3v.z), f2bf((v[3] - m) * rs * w3v.w + b3v.w) };
    *(u16x4*)&nc[row] = o;
}

// ---------------- final: out = nF + g2*(ca + g1*att2), only real rows
__global__ __launch_bounds__(256) void final_k(
    const float* __restrict__ nF, const float* __restrict__ ca,
    const float* __restrict__ att2, const float* __restrict__ g1,
    const float* __restrict__ g2, float* __restrict__ out, int sq, int sqp)
{
    const int q = blockIdx.x, b = blockIdx.y, tid = threadIdx.x;
    const size_t wrow = ((size_t)b * sqp + q) * 1024 + tid * 4;
    const size_t orow = ((size_t)b * sq + q) * 1024 + tid * 4;
    fx4 nf = *(const fx4*)&nF[wrow];
    fx4 c  = *(const fx4*)&ca[wrow];
    fx4 a2 = *(const fx4*)&att2[wrow];
    fx4 G1 = *(const fx4*)&g1[tid * 4];
    fx4 G2 = *(const fx4*)&g2[tid * 4];
    fx4 r;
    r.x = nf.x + G2.x * (c.x + G1.x * a2.x);
    r.y = nf.y + G2.y * (c.y + G1.y * a2.y);
    r.z = nf.z + G2.z * (c.z + G1.z * a2.z);
    r.w = nf.w + G2.w * (c.w + G1.w * a2.w);
    *(fx4*)&out[orow] = r;
}

extern "C" void kernel_launch(void* const* d_in, const int* in_sizes, int n_in,
                              void* d_out, int out_size, void* d_ws, size_t ws_size,
                              hipStream_t stream) {
    const float* x_in = (const float*)d_in[0];   // [8,13271,1024]
    const float* q_in = (const float*)d_in[1];   // [8,577,1024]
    const float* n1w = (const float*)d_in[2];
    const float* n1b = (const float*)d_in[3];
    const float* n2w = (const float*)d_in[4];
    const float* n2b = (const float*)d_in[5];
    const float* n3w = (const float*)d_in[6];
    const float* n3b = (const float*)d_in[7];
    const float* g1  = (const float*)d_in[8];
    const float* g2  = (const float*)d_in[9];
    const float* w1  = (const float*)d_in[10];
    const float* b1  = (const float*)d_in[11];
    const float* w2  = (const float*)d_in[12];
    const float* b2  = (const float*)d_in[13];
    float* out = (float*)d_out;

    const int B = 8, SQ = 577, SK = 13271, D = 1024;
    const int SQP = 640, SKP = 13312;
    const float scale = 0.03125f;

    char* ws = (char*)d_ws;
    size_t off = 0;
    auto alloc = [&](size_t n) { size_t o = off; off = (off + n + 255) & ~(size_t)255; return o; };
    u16*   Xn   = (u16*)  (ws + alloc((size_t)B * SKP * D * 2));
    u16*   Xt   = (u16*)  (ws + alloc((size_t)B * D * SKP * 2));
    u16*   Qb   = (u16*)  (ws + alloc((size_t)B * SQP * D * 2));
    float* nF   = (float*)(ws + alloc((size_t)B * SQP * D * 4));
    u16*   P    = (u16*)  (ws + alloc((size_t)B * SQP * SKP * 2));
    float* att  = (float*)(ws + alloc((size_t)B * SQP * D * 4));
    float* CA   = (float*)(ws + alloc((size_t)B * SQP * D * 4));
    u16*   NC   = (u16*)  (ws + alloc((size_t)B * SQP * D * 2));
    u16*   NCt  = (u16*)  (ws + alloc((size_t)B * D * SQP * 2));
    float* S2   = (float*)(ws + alloc((size_t)B * SQP * SQP * 4));
    u16*   P2   = (u16*)  (ws + alloc((size_t)B * SQP * SQP * 2));
    float* att2 = (float*)(ws + alloc((size_t)B * SQP * D * 4));
    const size_t perS1 = (size_t)SQP * SKP * 4;
    size_t room = (ws_size > off) ? (ws_size - off) / perS1 : 1;
    // cap at 4 batches: S1 chunk (136 MB) + Xn panel stays within the 256 MB L3
    int g = (int)(room < 1 ? 1 : (room > 4 ? 4 : room));
    float* S1 = (float*)(ws + off);
    (void)in_sizes; (void)n_in; (void)out_size;

    // 1. LayerNorms, wave-per-row (scale = 2^-5 folded into Qb exactly; softmax1 uses scale=1)
    ln_wave_k<<<dim3(SKP / 4, B), 256, 0, stream>>>(x_in, SK, SKP, n1w, n1b, Xn, nullptr, 1.0f);
    ln_wave_k<<<dim3(SQP / 4, B), 256, 0, stream>>>(q_in, SQ, SQP, n2w, n2b, Qb, nF, scale);

    // 2. V^T for the PV gemm
    transpose_k<<<dim3(D / 64, SKP / 64, B), 256, 0, stream>>>(
        Xn, Xt, SKP, D, (long)SKP * D, (long)SKP * D);

    // 3. cross-attn scores (256^2 8-phase) + softmax, L3-sized batch chunks
    for (int b = 0; b < B; b += g) {
        const int nb = (B - b) < g ? (B - b) : g;
        gemm256_qk<<<dim3(SKP / 256, 3, nb), 512, 0, stream>>>(
            Qb + (size_t)b * SQP * D, Xn + (size_t)b * SKP * D, S1,
            D / 64, D, D, SKP, (long)SQP * D, (long)SKP * D, (long)SQP * SKP, SQP);
        softmax_k<13><<<dim3(SQP, nb), 256, 0, stream>>>(
            S1, P + (size_t)b * SQP * SKP, SK, SKP, 1.0f,
            (long)SQP * SKP, (long)SQP * SKP);
    }

    // 4. attended = P @ V (256^2 8-phase, split-K x8), atomic into zeroed att
    hipMemsetAsync(att, 0, (size_t)B * SQP * D * 4, stream);
    gemm256_sk<8><<<dim3(D / 256, 3, B * 8), 512, 0, stream>>>(
        P, Xt, att, (SKP / 64) / 8, SKP, SKP, D,
        (long)SQP * SKP, (long)D * SKP, (long)SQP * D, SQP);

    // 5. MLP + LN3 (fused)
    mlp_ln_k<<<dim3(SQP, B), 256, 0, stream>>>(att, w1, b1, w2, b2, n3w, n3b, CA, NC, SQ);

    // 6. self-attention (128^2 split-K path, small)
    transpose_k<<<dim3(D / 64, SQP / 64, B), 256, 0, stream>>>(
        NC, NCt, SQP, D, (long)SQP * D, (long)SQP * D);
    hipMemsetAsync(S2, 0, (size_t)B * SQP * SQP * 4, stream);
    gemm_bt_sk<2><<<dim3(SQP / 128, SQP / 128, B * 2), 256, 0, stream>>>(
        NC, NC, S2, 16, D, D, SQP,
        (long)SQP * D, (long)SQP * D, (long)SQP * SQP);
    softmax_k<1><<<dim3(SQP, B), 256, 0, stream>>>(
        S2, P2, SQ, SQP, scale, (long)SQP * SQP, (long)SQP * SQP);
    hipMemsetAsync(att2, 0, (size_t)B * SQP * D * 4, stream);
    gemm_bt_sk<4><<<dim3(D / 128, SQP / 128, B * 4), 256, 0, stream>>>(
        P2, NCt, att2, 5, SQP, SQP, D,
        (long)SQP * SQP, (long)D * SQP, (long)SQP * D);

    // 7. final combine
    final_k<<<dim3(SQ, B), 256, 0, stream>>>(nF, CA, att2, g1, g2, out, SQ, SQP);
}

// Round 6
// 1275.174 us; speedup vs baseline: 1.0543x; 1.0543x over previous
//
#include <hip/hip_runtime.h>
#include <hip/hip_bf16.h>
#include <math.h>

typedef unsigned short u16;
typedef __attribute__((ext_vector_type(4))) unsigned short u16x4;
typedef __attribute__((ext_vector_type(8))) __bf16 bf16x8;
typedef __attribute__((ext_vector_type(4))) __bf16 bf16x4;
typedef __attribute__((ext_vector_type(4))) float fx4;

#define DEV __device__ __forceinline__

DEV u16 f2bf(float f) {  // RNE float->bf16
    unsigned u = __float_as_uint(f);
    u += 0x7fffu + ((u >> 16) & 1u);
    return (u16)(u >> 16);
}

DEV void async_load16(const void* g, void* l) {
    __builtin_amdgcn_global_load_lds(
        (const __attribute__((address_space(1))) void*)g,
        (__attribute__((address_space(3))) void*)l, 16, 0, 0);
}

DEV void block_reduce2(float& a, float& b) {
    #pragma unroll
    for (int o = 32; o; o >>= 1) { a += __shfl_xor(a, o); b += __shfl_xor(b, o); }
    __shared__ float sa[4], sb[4];
    const int lane = threadIdx.x & 63, wv = threadIdx.x >> 6;
    if (lane == 0) { sa[wv] = a; sb[wv] = b; }
    __syncthreads();
    a = sa[0] + sa[1] + sa[2] + sa[3];
    b = sb[0] + sb[1] + sb[2] + sb[3];
    __syncthreads();
}

// T1 XCD swizzle (chunked, bijective when total%8==0)
DEV void xcd_swizzle3(int& bx, int& by, int& bz) {
    const int nx = gridDim.x, ny = gridDim.y;
    const int total = nx * ny * gridDim.z;
    const int lin = blockIdx.x + nx * (blockIdx.y + ny * blockIdx.z);
    if (total & 7) { bx = blockIdx.x; by = blockIdx.y; bz = blockIdx.z; return; }
    const int cpx = total >> 3;
    const int swz = (lin & 7) * cpx + (lin >> 3);
    bx = swz % nx;
    const int r = swz / nx;
    by = r % ny;
    bz = r / ny;
}

// ---------------- LayerNorm, WAVE-per-row: no barriers, row lives in 16 VGPRs.
__global__ __launch_bounds__(256) void ln_wave_k(
    const float* __restrict__ in, int rows_real, int rows_pad,
    const float* __restrict__ w, const float* __restrict__ bias,
    u16* __restrict__ out_bf, float* __restrict__ out_f32, float out_scale)
{
    const int wv = threadIdx.x >> 6, lane = threadIdx.x & 63;
    const int r = blockIdx.x * 4 + wv, b = blockIdx.y;
    const size_t orow = ((size_t)b * rows_pad + r) * 1024 + lane * 4;
    if (r >= rows_real) {
        u16x4 z = {0, 0, 0, 0};
        fx4 zf = {0.f, 0.f, 0.f, 0.f};
        #pragma unroll
        for (int c = 0; c < 4; ++c) {
            *(u16x4*)&out_bf[orow + c * 256] = z;
            if (out_f32) *(fx4*)&out_f32[orow + c * 256] = zf;
        }
        return;
    }
    const size_t irow = ((size_t)b * rows_real + r) * 1024 + lane * 4;
    fx4 x[4];
    float s1 = 0.f, s2 = 0.f;
    #pragma unroll
    for (int c = 0; c < 4; ++c) {
        x[c] = *(const fx4*)&in[irow + c * 256];
        s1 += x[c].x + x[c].y + x[c].z + x[c].w;
        s2 += x[c].x * x[c].x + x[c].y * x[c].y + x[c].z * x[c].z + x[c].w * x[c].w;
    }
    #pragma unroll
    for (int o = 32; o; o >>= 1) { s1 += __shfl_xor(s1, o); s2 += __shfl_xor(s2, o); }
    const float m = s1 * (1.0f / 1024.0f);
    const float var = s2 * (1.0f / 1024.0f) - m * m;
    const float rs = rsqrtf(var + 1e-5f);
    #pragma unroll
    for (int c = 0; c < 4; ++c) {
        fx4 wv4 = *(const fx4*)&w[c * 256 + lane * 4];
        fx4 bv4 = *(const fx4*)&bias[c * 256 + lane * 4];
        fx4 y;
        y.x = (x[c].x - m) * rs * wv4.x + bv4.x;
        y.y = (x[c].y - m) * rs * wv4.y + bv4.y;
        y.z = (x[c].z - m) * rs * wv4.z + bv4.z;
        y.w = (x[c].w - m) * rs * wv4.w + bv4.w;
        u16x4 o = { f2bf(y.x * out_scale), f2bf(y.y * out_scale),
                    f2bf(y.z * out_scale), f2bf(y.w * out_scale) };
        *(u16x4*)&out_bf[orow + c * 256] = o;
        if (out_f32) *(fx4*)&out_f32[orow + c * 256] = y;
    }
}

// ---------------- 128x128 bf16 GEMM core (2-phase dbuf) — small self-attn gemms only
template<bool ATOMIC>
DEV void gemm_body(
    const u16* __restrict__ Ab, const u16* __restrict__ Bb, float* __restrict__ Cb,
    int k_begin, int iters, int lda, int ldb, int ldc)
{
    __shared__ u16 lA[2][128 * 32];
    __shared__ u16 lB[2][128 * 32];
    const int lane = threadIdx.x & 63, wv = threadIdx.x >> 6;
    const int wm = (wv >> 1) * 64, wn = (wv & 1) * 64;
    const int frow = lane & 15, quad = lane >> 4;

    fx4 acc[4][4];
    #pragma unroll
    for (int i = 0; i < 4; ++i)
        #pragma unroll
        for (int j = 0; j < 4; ++j) { acc[i][j].x = 0; acc[i][j].y = 0; acc[i][j].z = 0; acc[i][j].w = 0; }

    const int c0 = wv * 64 + lane;
    const int r0a = c0 >> 2, s0 = (c0 & 3) * 8;
    const int c1 = 256 + c0;
    const int r1a = c1 >> 2, s1 = (c1 & 3) * 8;

    auto stage = [&](int buf, int it) {
        const int k0 = k_begin + it * 32;
        async_load16(Ab + (size_t)r0a * lda + k0 + s0, &lA[buf][(wv * 64) * 8]);
        async_load16(Ab + (size_t)r1a * lda + k0 + s1, &lA[buf][(256 + wv * 64) * 8]);
        async_load16(Bb + (size_t)r0a * ldb + k0 + s0, &lB[buf][(wv * 64) * 8]);
        async_load16(Bb + (size_t)r1a * ldb + k0 + s1, &lB[buf][(256 + wv * 64) * 8]);
    };

    stage(0, 0);
    __syncthreads();
    int cur = 0;
    for (int it = 0; it < iters; ++it) {
        if (it + 1 < iters) stage(cur ^ 1, it + 1);
        bf16x8 af[4], bfr[4];
        #pragma unroll
        for (int i = 0; i < 4; ++i) {
            af[i]  = *(const bf16x8*)&lA[cur][(wm + i * 16 + frow) * 32 + quad * 8];
            bfr[i] = *(const bf16x8*)&lB[cur][(wn + i * 16 + frow) * 32 + quad * 8];
        }
        #pragma unroll
        for (int mi = 0; mi < 4; ++mi)
            #pragma unroll
            for (int ni = 0; ni < 4; ++ni)
                acc[mi][ni] = __builtin_amdgcn_mfma_f32_16x16x32_bf16(af[mi], bfr[ni], acc[mi][ni], 0, 0, 0);
        __syncthreads();
        cur ^= 1;
    }

    #pragma unroll
    for (int mi = 0; mi < 4; ++mi) {
        #pragma unroll
        for (int r = 0; r < 4; ++r) {
            const int row = wm + mi * 16 + quad * 4 + r;
            #pragma unroll
            for (int ni = 0; ni < 4; ++ni) {
                const int col = wn + ni * 16 + frow;
                if (ATOMIC) atomicAdd(&Cb[(size_t)row * ldc + col], acc[mi][ni][r]);
                else        Cb[(size_t)row * ldc + col] = acc[mi][ni][r];
            }
        }
    }
}

template<int NS>
__global__ __launch_bounds__(256) void gemm_bt_sk(
    const u16* __restrict__ A, const u16* __restrict__ B, float* __restrict__ C,
    int iters_per, int lda, int ldb, int ldc, long As, long Bs, long Cs)
{
    int bx, by, bzz;
    xcd_swizzle3(bx, by, bzz);
    const int bz = bzz / NS, sp = bzz % NS;
    const u16* Ab = A + (size_t)bz * As + (size_t)by * 128 * lda;
    const u16* Bb = B + (size_t)bz * Bs + (size_t)bx * 128 * ldb;
    float* Cb = C + (size_t)bz * Cs + (size_t)by * 128 * ldc + (size_t)bx * 128;
    gemm_body<true>(Ab, Bb, Cb, sp * iters_per * 32, iters_per, lda, ldb, ldc);
}

// ================= 256x256 8-phase GEMM =================================================
// BTRANS=false (QK^T): B rows are k-major like A (B = Xn, k = d). Proven schedule.
// BTRANS=true  (PV): B = Xn consumed TRANSPOSED via ds_read_b64_tr_b16. V-tile stored
//   row-major [64 sk][256 d] across regions B0 (sk 0..31) + B1 (sk 32..63); staging is
//   global_load_lds-direct with source-chunk XOR (cc ^= rl&7, 16B chunks) and the read
//   applies the matching XOR (rule 21). tr crossbar (m156/m162): per 16-lane group,
//   lane g loads 8B; lane l receives elems {16j + (l&15)} of the group's 128B.
//   vmcnt: B1(cur) staged t-1.p1 -> p0 wait = 6; peeled (2,2,0,0).
template<bool ATOMIC, bool BTRANS>
DEV void gemm256_body(
    const u16* __restrict__ A, const u16* __restrict__ B, float* __restrict__ C,
    int k_begin, int NT, int lda, int ldb, int ldc, int bx, int by, int Mreal)
{
    __shared__ u16 lds[2][4][8192];   // [buf][A0,A1,B0,B1][8192 u16]
    const int tid = threadIdx.x;
    const int lane = tid & 63, wid = tid >> 6;
    const int wr = wid >> 2, wc = wid & 3;
    const int frow = lane & 15, quad = lane >> 4;
    const int sw = (frow & 7) << 4;                 // A-side T2 read XOR (bytes)
    const int csrc = ((lane & 7) ^ ((lane >> 3) & 7)) * 8;  // A-side pre-swizzled source chunk
    const int by256 = by * 256, bx256 = bx * 256;
    const int mclamp = Mreal - 1;
    const unsigned ldsb0 = (unsigned)(size_t)(__attribute__((address_space(3))) void*)&lds[0][2][0];
    const unsigned ldsb1 = (unsigned)(size_t)(__attribute__((address_space(3))) void*)&lds[1][2][0];

    fx4 acc[8][4];
    #pragma unroll
    for (int i = 0; i < 8; ++i)
        #pragma unroll
        for (int j = 0; j < 4; ++j) { acc[i][j].x = 0; acc[i][j].y = 0; acc[i][j].z = 0; acc[i][j].w = 0; }

    auto stA = [&](int buf, int half, int ktile) {
        const int kcol = k_begin + ktile * 64;
        #pragma unroll
        for (int j = 0; j < 2; ++j) {
            int grow = by256 + half * 128 + (wid * 2 + j) * 8 + (lane >> 3);
            if (grow > mclamp) grow = mclamp;
            async_load16(A + (size_t)grow * lda + kcol + csrc,
                         &lds[buf][half][(wid * 2 + j) * 512]);
        }
    };
    auto stB = [&](int buf, int half, int ktile) {
        if constexpr (BTRANS) {
            const int kb = k_begin + ktile * 64 + half * 32;
            #pragma unroll
            for (int j = 0; j < 2; ++j) {
                const int rl = (wid * 2 + j) * 2 + (lane >> 5);      // row within half (0..31)
                const int cc = (lane & 31) ^ (rl & 7);               // source 16B-chunk (swizzled)
                async_load16(B + (size_t)(kb + rl) * ldb + bx256 + cc * 8,
                             &lds[buf][2 + half][(wid * 2 + j) * 512]);
            }
        } else {
            const int kcol = k_begin + ktile * 64;
            #pragma unroll
            for (int j = 0; j < 2; ++j) {
                const int grow = bx256 + half * 128 + (wid * 2 + j) * 8 + (lane >> 3);
                async_load16(B + (size_t)grow * ldb + kcol + csrc,
                             &lds[buf][2 + half][(wid * 2 + j) * 512]);
            }
        }
    };

#define DO_PHASE(MQ, NQ, STAGE_STMT, WAITN)                                              \
    {                                                                                    \
        STAGE_STMT;                                                                      \
        __builtin_amdgcn_sched_barrier(0);                                               \
        asm volatile("s_waitcnt vmcnt(%0)" :: "i"(WAITN) : "memory");                    \
        __builtin_amdgcn_s_barrier();                                                    \
        __builtin_amdgcn_sched_barrier(0);                                               \
        const char* pa = (const char*)&lds[cur][MQ][0];                                  \
        bf16x8 av[4][2], bv[2][2];                                                       \
        _Pragma("unroll")                                                                \
        for (int f = 0; f < 4; ++f) {                                                    \
            const int row = wr * 64 + f * 16 + frow;                                     \
            _Pragma("unroll")                                                            \
            for (int ks = 0; ks < 2; ++ks)                                               \
                av[f][ks] = *(const bf16x8*)(pa + row * 128 + ((((ks * 4 + quad) << 4)) ^ sw)); \
        }                                                                                \
        if constexpr (BTRANS) {                                                          \
            const unsigned bB = cur ? ldsb1 : ldsb0;                                     \
            _Pragma("unroll")                                                            \
            for (int gg = 0; gg < 2; ++gg)                                               \
                _Pragma("unroll")                                                        \
                for (int ks = 0; ks < 2; ++ks) {                                         \
                    const int rlo = ks * 32 + quad * 8 + ((lane & 15) >> 2);             \
                    const int ob = ((NQ) * 128 + wc * 32 + gg * 16 + 4 * (lane & 3)) * 2;\
                    const unsigned alo = bB + rlo * 512 + (ob ^ ((rlo & 7) << 4));       \
                    const unsigned ahi = bB + (rlo + 4) * 512 + (ob ^ (((rlo + 4) & 7) << 4)); \
                    bf16x4 plo, phi;                                                     \
                    asm volatile("ds_read_b64_tr_b16 %0, %2\n\t"                        \
                                 "ds_read_b64_tr_b16 %1, %3"                            \
                                 : "=v"(plo), "=v"(phi) : "v"(alo), "v"(ahi));           \
                    bv[gg][ks] = __builtin_shufflevector(plo, phi, 0, 1, 2, 3, 4, 5, 6, 7); \
                }                                                                        \
            asm volatile("s_waitcnt lgkmcnt(0)" ::: "memory");                           \
            __builtin_amdgcn_sched_barrier(0);                                           \
        } else {                                                                         \
            const char* pb = (const char*)&lds[cur][2 + NQ][0];                          \
            _Pragma("unroll")                                                            \
            for (int gg = 0; gg < 2; ++gg) {                                             \
                const int col = wc * 32 + gg * 16 + frow;                                \
                _Pragma("unroll")                                                        \
                for (int ks = 0; ks < 2; ++ks)                                           \
                    bv[gg][ks] = *(const bf16x8*)(pb + col * 128 + ((((ks * 4 + quad) << 4)) ^ sw)); \
            }                                                                            \
        }                                                                                \
        __builtin_amdgcn_s_setprio(1);                                                   \
        _Pragma("unroll")                                                                \
        for (int f = 0; f < 4; ++f)                                                      \
            _Pragma("unroll")                                                            \
            for (int gg = 0; gg < 2; ++gg)                                               \
                _Pragma("unroll")                                                        \
                for (int ks = 0; ks < 2; ++ks)                                           \
                    acc[MQ * 4 + f][NQ * 2 + gg] = __builtin_amdgcn_mfma_f32_16x16x32_bf16( \
                        av[f][ks], bv[gg][ks], acc[MQ * 4 + f][NQ * 2 + gg], 0, 0, 0);   \
        __builtin_amdgcn_s_setprio(0);                                                   \
    }

    // prologue stage order: A0(0), B0(0), B1(0), A1(0), A0(1)
    stA(0, 0, 0);
    stB(0, 0, 0);
    stB(0, 1, 0);
    stA(0, 1, 0);
    stA(1, 0, 1);

    int cur = 0;
    for (int t = 0; t <= NT - 2; ++t) {
        const int nxt = cur ^ 1;
        DO_PHASE(0, 0, stB(nxt, 0, t + 1), (BTRANS ? 6 : 8))
        DO_PHASE(0, 1, stB(nxt, 1, t + 1), 8)
        DO_PHASE(1, 0, stA(nxt, 1, t + 1), 8)
        DO_PHASE(1, 1, if (t + 2 < NT) stA(cur, 0, t + 2), 8)
        cur = nxt;
    }
    // peeled last tile: no stages, draining counted waits
    DO_PHASE(0, 0, (void)0, (BTRANS ? 2 : 4))
    DO_PHASE(0, 1, (void)0, 2)
    DO_PHASE(1, 0, (void)0, 0)
    DO_PHASE(1, 1, (void)0, 0)
#undef DO_PHASE

    #pragma unroll
    for (int mf = 0; mf < 8; ++mf) {
        const int rowb = (mf >> 2) * 128 + wr * 64 + (mf & 3) * 16 + quad * 4;
        #pragma unroll
        for (int r = 0; r < 4; ++r) {
            const int grow = by256 + rowb + r;
            if (grow < Mreal) {
                #pragma unroll
                for (int nf = 0; nf < 4; ++nf) {
                    const int gcol = bx256 + (nf >> 1) * 128 + wc * 32 + (nf & 1) * 16 + frow;
                    if (ATOMIC) atomicAdd(&C[(size_t)grow * ldc + gcol], acc[mf][nf][r]);
                    else C[(size_t)grow * ldc + gcol] = acc[mf][nf][r];
                }
            }
        }
    }
}

// QK^T: bx-major remap (A panel stays cache-resident)
__global__ __launch_bounds__(512, 2) void gemm256_qk(
    const u16* __restrict__ A, const u16* __restrict__ B, float* __restrict__ C,
    int NT, int lda, int ldb, int ldc, long As, long Bs, long Cs, int Mreal)
{
    const int lin = blockIdx.x + gridDim.x * (blockIdx.y + gridDim.y * blockIdx.z);
    const int per_bx = gridDim.y * gridDim.z;
    const int bx = lin / per_bx, rem = lin % per_bx;
    const int by = rem % gridDim.y, bz = rem / gridDim.y;
    gemm256_body<false, false>(A + (size_t)bz * As, B + (size_t)bz * Bs, C + (size_t)bz * Cs,
                               0, NT, lda, ldb, ldc, bx, by, Mreal);
}

// PV: split-K, XCD-chunked swizzle, atomic into pre-zeroed C; B = Xn consumed via tr-read
template<int NS>
__global__ __launch_bounds__(512, 2) void gemm256_sk(
    const u16* __restrict__ A, const u16* __restrict__ B, float* __restrict__ C,
    int NT_per, int lda, int ldb, int ldc, long As, long Bs, long Cs, int Mreal)
{
    int bx, by, bzz;
    xcd_swizzle3(bx, by, bzz);
    const int bz = bzz / NS, sp = bzz % NS;
    gemm256_body<true, true>(A + (size_t)bz * As, B + (size_t)bz * Bs, C + (size_t)bz * Cs,
                             sp * NT_per * 64, NT_per, lda, ldb, ldc, bx, by, Mreal);
}

// ---------------- row softmax (fx4-vectorized)
template<int EPT4>
__global__ __launch_bounds__(256) void softmax_k(
    const float* __restrict__ S, u16* __restrict__ P,
    int n_real, int n_pad, float scale, long Ss, long Ps)
{
    const int tid = threadIdx.x;
    const float* Sr = S + (size_t)blockIdx.y * Ss + (size_t)blockIdx.x * n_pad;
    u16* Pr = P + (size_t)blockIdx.y * Ps + (size_t)blockIdx.x * n_pad;
    fx4 v[EPT4];
    float mx = -INFINITY;
    #pragma unroll
    for (int i = 0; i < EPT4; ++i) {
        const int base = (i * 256 + tid) * 4;
        fx4 s;
        if (base < n_pad) s = *(const fx4*)&Sr[base];
        else { s.x = -INFINITY; s.y = -INFINITY; s.z = -INFINITY; s.w = -INFINITY; }
        s.x = (base + 0 < n_real) ? s.x * scale : -INFINITY;
        s.y = (base + 1 < n_real) ? s.y * scale : -INFINITY;
        s.z = (base + 2 < n_real) ? s.z * scale : -INFINITY;
        s.w = (base + 3 < n_real) ? s.w * scale : -INFINITY;
        v[i] = s;
        mx = fmaxf(mx, fmaxf(fmaxf(s.x, s.y), fmaxf(s.z, s.w)));
    }
    #pragma unroll
    for (int o = 32; o; o >>= 1) mx = fmaxf(mx, __shfl_xor(mx, o));
    __shared__ float sm[4];
    const int lane = tid & 63, wvi = tid >> 6;
    if (lane == 0) sm[wvi] = mx;
    __syncthreads();
    mx = fmaxf(fmaxf(sm[0], sm[1]), fmaxf(sm[2], sm[3]));
    __syncthreads();
    float sum = 0.f;
    #pragma unroll
    for (int i = 0; i < EPT4; ++i) {
        fx4 e;
        e.x = __expf(v[i].x - mx); e.y = __expf(v[i].y - mx);
        e.z = __expf(v[i].z - mx); e.w = __expf(v[i].w - mx);
        v[i] = e;
        sum += e.x + e.y + e.z + e.w;
    }
    #pragma unroll
    for (int o = 32; o; o >>= 1) sum += __shfl_xor(sum, o);
    if (lane == 0) sm[wvi] = sum;
    __syncthreads();
    sum = sm[0] + sm[1] + sm[2] + sm[3];
    const float inv = 1.0f / sum;
    #pragma unroll
    for (int i = 0; i < EPT4; ++i) {
        const int base = (i * 256 + tid) * 4;
        if (base < n_pad) {
            u16x4 o = { f2bf(v[i].x * inv), f2bf(v[i].y * inv),
                        f2bf(v[i].z * inv), f2bf(v[i].w * inv) };
            *(u16x4*)&Pr[base] = o;
        }
    }
}

// ---------------- bf16 transpose, 64x64 tile (small NCt only)
__global__ __launch_bounds__(256) void transpose_k(
    const u16* __restrict__ in, u16* __restrict__ out,
    int in_rows, int in_cols, long is, long os)
{
    __shared__ u16 t[64][68];
    const int b = blockIdx.z;
    const u16* I = in + (size_t)b * is;
    u16* O = out + (size_t)b * os;
    const int c0 = blockIdx.x * 64, r0 = blockIdx.y * 64;
    const int cx = threadIdx.x & 15, ry = threadIdx.x >> 4;
    u16x4 a[4];
    #pragma unroll
    for (int k = 0; k < 4; ++k)
        a[k] = *(const u16x4*)&I[(size_t)(r0 + 4 * ry + k) * in_cols + c0 + 4 * cx];
    #pragma unroll
    for (int e = 0; e < 4; ++e) {
        u16x4 o = { a[0][e], a[1][e], a[2][e], a[3][e] };
        *(u16x4*)&t[4 * cx + e][4 * ry] = o;
    }
    __syncthreads();
    #pragma unroll
    for (int k = 0; k < 4; ++k) {
        const int oc = 4 * ry + k;
        *(u16x4*)&O[(size_t)(c0 + oc) * in_rows + r0 + 4 * cx] =
            *(const u16x4*)&t[oc][4 * cx];
    }
}

// ---------------- fused MLP (H=4, exact-erf GELU) + LayerNorm3; block per row
__global__ __launch_bounds__(256) void mlp_ln_k(
    const float* __restrict__ att, const float* __restrict__ w1, const float* __restrict__ b1,
    const float* __restrict__ w2, const float* __restrict__ b2,
    const float* __restrict__ w3, const float* __restrict__ b3,
    float* __restrict__ ca, u16* __restrict__ nc, int rows_real)
{
    const int q = blockIdx.x, b = blockIdx.y, tid = threadIdx.x;
    const size_t row = ((size_t)b * gridDim.x + q) * 1024 + tid * 4;
    if (q >= rows_real) {
        fx4 zf = {0.f, 0.f, 0.f, 0.f}; u16x4 z = {0, 0, 0, 0};
        *(fx4*)&ca[row] = zf;
        *(u16x4*)&nc[row] = z;
        return;
    }
    fx4 x = *(const fx4*)&att[row];
    float p[4];
    #pragma unroll
    for (int j = 0; j < 4; ++j) {
        fx4 wj = *(const fx4*)&w1[j * 1024 + tid * 4];
        p[j] = x.x * wj.x + x.y * wj.y + x.z * wj.z + x.w * wj.w;
        #pragma unroll
        for (int o = 32; o; o >>= 1) p[j] += __shfl_xor(p[j], o);
    }
    __shared__ float sh[4][4];
    const int lane = tid & 63, wvi = tid >> 6;
    if (lane == 0) { sh[wvi][0] = p[0]; sh[wvi][1] = p[1]; sh[wvi][2] = p[2]; sh[wvi][3] = p[3]; }
    __syncthreads();
    float h[4];
    #pragma unroll
    for (int j = 0; j < 4; ++j) {
        float s = sh[0][j] + sh[1][j] + sh[2][j] + sh[3][j] + b1[j];
        h[j] = 0.5f * s * (1.0f + erff(s * 0.70710678118f));
    }
    float v[4]; float s1 = 0.f, s2 = 0.f;
    #pragma unroll
    for (int e = 0; e < 4; ++e) {
        const int d = tid * 4 + e;
        fx4 wd = *(const fx4*)&w2[d * 4];
        float t = h[0] * wd.x + h[1] * wd.y + h[2] * wd.z + h[3] * wd.w + b2[d];
        v[e] = t; s1 += t; s2 += t * t;
    }
    block_reduce2(s1, s2);
    const float m = s1 * (1.0f / 1024.0f);
    const float var = s2 * (1.0f / 1024.0f) - m * m;
    const float rs = rsqrtf(var + 1e-5f);
    fx4 cav = {v[0], v[1], v[2], v[3]};
    *(fx4*)&ca[row] = cav;
    fx4 w3v = *(const fx4*)&w3[tid * 4], b3v = *(const fx4*)&b3[tid * 4];
    u16x4 o = { f2bf((v[0] - m) * rs * w3v.x + b3v.x), f2bf((v[1] - m) * rs * w3v.y + b3v.y),
                f2bf((v[2] - m) * rs * w3v.z + b3v.z), f2bf((v[3] - m) * rs * w3v.w + b3v.w) };
    *(u16x4*)&nc[row] = o;
}

// ---------------- final: out = nF + g2*(ca + g1*att2), only real rows
__global__ __launch_bounds__(256) void final_k(
    const float* __restrict__ nF, const float* __restrict__ ca,
    const float* __restrict__ att2, const float* __restrict__ g1,
    const float* __restrict__ g2, float* __restrict__ out, int sq, int sqp)
{
    const int q = blockIdx.x, b = blockIdx.y, tid = threadIdx.x;
    const size_t wrow = ((size_t)b * sqp + q) * 1024 + tid * 4;
    const size_t orow = ((size_t)b * sq + q) * 1024 + tid * 4;
    fx4 nf = *(const fx4*)&nF[wrow];
    fx4 c  = *(const fx4*)&ca[wrow];
    fx4 a2 = *(const fx4*)&att2[wrow];
    fx4 G1 = *(const fx4*)&g1[tid * 4];
    fx4 G2 = *(const fx4*)&g2[tid * 4];
    fx4 r;
    r.x = nf.x + G2.x * (c.x + G1.x * a2.x);
    r.y = nf.y + G2.y * (c.y + G1.y * a2.y);
    r.z = nf.z + G2.z * (c.z + G1.z * a2.z);
    r.w = nf.w + G2.w * (c.w + G1.w * a2.w);
    *(fx4*)&out[orow] = r;
}

extern "C" void kernel_launch(void* const* d_in, const int* in_sizes, int n_in,
                              void* d_out, int out_size, void* d_ws, size_t ws_size,
                              hipStream_t stream) {
    const float* x_in = (const float*)d_in[0];   // [8,13271,1024]
    const float* q_in = (const float*)d_in[1];   // [8,577,1024]
    const float* n1w = (const float*)d_in[2];
    const float* n1b = (const float*)d_in[3];
    const float* n2w = (const float*)d_in[4];
    const float* n2b = (const float*)d_in[5];
    const float* n3w = (const float*)d_in[6];
    const float* n3b = (const float*)d_in[7];
    const float* g1  = (const float*)d_in[8];
    const float* g2  = (const float*)d_in[9];
    const float* w1  = (const float*)d_in[10];
    const float* b1  = (const float*)d_in[11];
    const float* w2  = (const float*)d_in[12];
    const float* b2  = (const float*)d_in[13];
    float* out = (float*)d_out;

    const int B = 8, SQ = 577, SK = 13271, D = 1024;
    const int SQP = 640, SKP = 13312;
    const float scale = 0.03125f;

    char* ws = (char*)d_ws;
    size_t off = 0;
    auto alloc = [&](size_t n) { size_t o = off; off = (off + n + 255) & ~(size_t)255; return o; };
    u16*   Xn   = (u16*)  (ws + alloc((size_t)B * SKP * D * 2));
    u16*   Qb   = (u16*)  (ws + alloc((size_t)B * SQP * D * 2));
    float* nF   = (float*)(ws + alloc((size_t)B * SQP * D * 4));
    u16*   P    = (u16*)  (ws + alloc((size_t)B * SQP * SKP * 2));
    float* att  = (float*)(ws + alloc((size_t)B * SQP * D * 4));
    float* CA   = (float*)(ws + alloc((size_t)B * SQP * D * 4));
    u16*   NC   = (u16*)  (ws + alloc((size_t)B * SQP * D * 2));
    u16*   NCt  = (u16*)  (ws + alloc((size_t)B * D * SQP * 2));
    float* S2   = (float*)(ws + alloc((size_t)B * SQP * SQP * 4));
    u16*   P2   = (u16*)  (ws + alloc((size_t)B * SQP * SQP * 2));
    float* att2 = (float*)(ws + alloc((size_t)B * SQP * D * 4));
    const size_t perS1 = (size_t)SQP * SKP * 4;
    size_t room = (ws_size > off) ? (ws_size - off) / perS1 : 1;
    int g = (int)(room < 1 ? 1 : (room > 8 ? 8 : room));
    float* S1 = (float*)(ws + off);
    (void)in_sizes; (void)n_in; (void)out_size;

    // 1. LayerNorms, wave-per-row (scale = 2^-5 folded into Qb exactly; softmax1 uses scale=1)
    ln_wave_k<<<dim3(SKP / 4, B), 256, 0, stream>>>(x_in, SK, SKP, n1w, n1b, Xn, nullptr, 1.0f);
    ln_wave_k<<<dim3(SQP / 4, B), 256, 0, stream>>>(q_in, SQ, SQP, n2w, n2b, Qb, nF, scale);

    // 2. cross-attn scores (256^2 8-phase) + softmax, batches grouped by S1 room
    for (int b = 0; b < B; b += g) {
        const int nb = (B - b) < g ? (B - b) : g;
        gemm256_qk<<<dim3(SKP / 256, 3, nb), 512, 0, stream>>>(
            Qb + (size_t)b * SQP * D, Xn + (size_t)b * SKP * D, S1,
            D / 64, D, D, SKP, (long)SQP * D, (long)SKP * D, (long)SQP * SKP, SQP);
        softmax_k<13><<<dim3(SQP, nb), 256, 0, stream>>>(
            S1, P + (size_t)b * SQP * SKP, SK, SKP, 1.0f,
            (long)SQP * SKP, (long)SQP * SKP);
    }

    // 3. attended = P @ V (V = Xn, transposed in-kernel via tr-read), split-K x8
    hipMemsetAsync(att, 0, (size_t)B * SQP * D * 4, stream);
    gemm256_sk<8><<<dim3(D / 256, 3, B * 8), 512, 0, stream>>>(
        P, Xn, att, (SKP / 64) / 8, SKP, D, D,
        (long)SQP * SKP, (long)SKP * D, (long)SQP * D, SQP);

    // 4. MLP + LN3 (fused)
    mlp_ln_k<<<dim3(SQP, B), 256, 0, stream>>>(att, w1, b1, w2, b2, n3w, n3b, CA, NC, SQ);

    // 5. self-attention (128^2 split-K path, small)
    transpose_k<<<dim3(D / 64, SQP / 64, B), 256, 0, stream>>>(
        NC, NCt, SQP, D, (long)SQP * D, (long)SQP * D);
    hipMemsetAsync(S2, 0, (size_t)B * SQP * SQP * 4, stream);
    gemm_bt_sk<2><<<dim3(SQP / 128, SQP / 128, B * 2), 256, 0, stream>>>(
        NC, NC, S2, 16, D, D, SQP,
        (long)SQP * D, (long)SQP * D, (long)SQP * SQP);
    softmax_k<1><<<dim3(SQP, B), 256, 0, stream>>>(
        S2, P2, SQ, SQP, scale, (long)SQP * SQP, (long)SQP * SQP);
    hipMemsetAsync(att2, 0, (size_t)B * SQP * D * 4, stream);
    gemm_bt_sk<4><<<dim3(D / 128, SQP / 128, B * 4), 256, 0, stream>>>(
        P2, NCt, att2, 5, SQP, SQP, D,
        (long)SQP * SQP, (long)D * SQP, (long)SQP * D);

    // 6. final combine
    final_k<<<dim3(SQ, B), 256, 0, stream>>>(nF, CA, att2, g1, g2, out, SQ, SQP);
}